// Round 1
// 505.404 us; speedup vs baseline: 1.1849x; 1.1849x over previous
//
#include <hip/hip_runtime.h>

// GraphConvLayer: B=32, C=64, T=64, V=325, Ks=2. f32 in/out, bf16 MFMA compute.
// out[b,c,t,v] = x[b,c,t,v] + bias[c]
//              + sum_i W0[i,c] x[b,i,t,v]
//              + sum_i W1[i,c] * (sum_u x[b,i,t,u] gso[v,u])
//
// R1: 512 -> 1024 threads/block. LDS (142.8 KB) caps us at 1 block/CU, so the
// only way to raise waves/SIMD (2 -> 4) without an LDS rewrite is a fatter
// block. All phase work splits are per-wave-indexed, so only the strides and
// the m/n-tile stepping change.

typedef __bf16 bf16x8 __attribute__((ext_vector_type(8)));
typedef float f32x4 __attribute__((ext_vector_type(4)));

#define XROW 360   // Xr row stride (elems): >=352, 180dw%32=20 -> 2-way banks max
#define TROW 72    // Xt/Yt row stride: >=64, 36dw%32=4 -> 2-way banks max
#define GROW 352   // gso_pad row stride (11 k-tiles of 32)
#define VPAD 336   // 21 n-tiles of 16

__device__ __forceinline__ float bf2f(unsigned short u) {
  union { unsigned int i; float f; } t;
  t.i = ((unsigned int)u) << 16;
  return t.f;
}
__device__ __forceinline__ unsigned short f2bf(float f) {
  union { float f; unsigned int i; } t;
  t.f = f;
  unsigned int u = t.i;
  unsigned int r = (u + 0x7fffu + ((u >> 16) & 1u)) >> 16;  // RNE
  return (unsigned short)r;
}

// Builds bf16 gso_pad[336][352] (zero-padded) and bf16 Wt[k][c][i] = weight[k][i][c].
__global__ void prep_kernel(const float* __restrict__ gso,
                            const float* __restrict__ weight,
                            unsigned short* __restrict__ gso_pad,
                            unsigned short* __restrict__ wt) {
  int idx = blockIdx.x * 256 + threadIdx.x;
  if (idx < VPAD * GROW) {
    int v = idx / GROW, u = idx - v * GROW;
    unsigned short val = 0;
    if (v < 325 && u < 325) val = f2bf(gso[v * 325 + u]);
    gso_pad[idx] = val;
  }
  if (idx < 2 * 64 * 64) {
    int k = idx >> 12, r = idx & 4095, c = r >> 6, i = r & 63;
    wt[idx] = f2bf(weight[(k << 12) | (i << 6) | c]);
  }
}

__global__ __launch_bounds__(1024, 4) void gconv_kernel(
    const float* __restrict__ x,
    const float* __restrict__ bias,
    const unsigned short* __restrict__ gso_pad,
    const unsigned short* __restrict__ wt,
    float* __restrict__ out) {
  __shared__ unsigned short Xr[64 * XROW];    // bf16 x[c][u], u in [325,352) zero
  __shared__ unsigned short Xt[VPAD * TROW];  // bf16 x^T[v][c], rows [325,336) zero
  __shared__ unsigned short Yt[VPAD * TROW];  // bf16 Y^T[v][c]

  const int bid = blockIdx.x;
  const int b = bid >> 6, t = bid & 63;
  const int tid = threadIdx.x;
  const int xbase = b * 1331200 + t * 325;  // + c*20800 + v (f32 elems)

  // ---- Stage 1: global f32 -> bf16 Xr (coalesced) ----
#pragma unroll 4
  for (int idx = tid; idx < 64 * 352; idx += 1024) {
    int c = idx / 352, u = idx - c * 352;
    float val = (u < 325) ? x[xbase + c * 20800 + u] : 0.f;
    Xr[c * XROW + u] = f2bf(val);
  }
  __syncthreads();
  // ---- Stage 2: LDS transpose Xr -> Xt ----
  for (int idx = tid; idx < 16 * VPAD; idx += 1024) {
    int c4 = idx / VPAD, v = idx - c4 * VPAD;
    int c = c4 * 4;
    ushort4 w;
    w.x = Xr[(c + 0) * XROW + v];  // zero for v>=325 (padded cols)
    w.y = Xr[(c + 1) * XROW + v];
    w.z = Xr[(c + 2) * XROW + v];
    w.w = Xr[(c + 3) * XROW + v];
    *reinterpret_cast<ushort4*>(&Xt[v * TROW + c]) = w;
  }
  __syncthreads();

  const int wid = tid >> 6, lane = tid & 63;
  const int quad = lane >> 4, l16 = lane & 15;
  const int koff = quad * 8;  // A/B frag: k = s*32 + quad*8 + j

  // ---- Phase A: Yt[v][c] = sum_u gso[v,u] * x[c][u]  (M=v, N=c, K=352) ----
  {
    const int cn = (wid & 3) * 16;  // n-tile (c)
    bf16x8 bX[11];                  // B-frags: Xr rows, reused across all m-tiles
#pragma unroll
    for (int s = 0; s < 11; ++s)
      bX[s] = *reinterpret_cast<const bf16x8*>(&Xr[(cn + l16) * XROW + s * 32 + koff]);
    for (int m = (wid >> 2); m < 21; m += 4) {
      const int vb = m * 16;
      const unsigned short* gp = &gso_pad[(vb + l16) * GROW + koff];
      f32x4 acc = {0.f, 0.f, 0.f, 0.f};
#pragma unroll
      for (int s = 0; s < 11; ++s) {
        bf16x8 ag = *reinterpret_cast<const bf16x8*>(gp + s * 32);  // A: gso row (L2-hot)
        acc = __builtin_amdgcn_mfma_f32_16x16x32_bf16(ag, bX[s], acc, 0, 0, 0);
      }
      const int vr = vb + quad * 4;  // C/D: row = v-offset, col = c-offset
#pragma unroll
      for (int r = 0; r < 4; ++r)
        Yt[(vr + r) * TROW + cn + l16] = f2bf(acc[r]);  // lanes contiguous
    }
  }
  __syncthreads();

  // ---- Phase B: out[c][v] = W0^T@X + W1^T@Y + bias + residual ----
  {
    const int cb = (wid & 3) * 16;  // m-tile (c)
    bf16x8 aW[4];                   // A-frags: k-concat [W0 i0..63 | W1 i0..63]
#pragma unroll
    for (int s = 0; s < 4; ++s)
      aW[s] = *reinterpret_cast<const bf16x8*>(
          &wt[((s >> 1) * 64 + cb + l16) * 64 + (s & 1) * 32 + koff]);
    float bias_f[4];
#pragma unroll
    for (int r = 0; r < 4; ++r) bias_f[r] = bias[cb + quad * 4 + r];

    for (int n = (wid >> 2); n < 21; n += 4) {
      const int vb = n * 16;
      const unsigned short* tp = &Xt[(vb + l16) * TROW + koff];
      const unsigned short* yp = &Yt[(vb + l16) * TROW + koff];
      bf16x8 bx0 = *reinterpret_cast<const bf16x8*>(tp);
      bf16x8 bx1 = *reinterpret_cast<const bf16x8*>(tp + 32);
      bf16x8 by0 = *reinterpret_cast<const bf16x8*>(yp);
      bf16x8 by1 = *reinterpret_cast<const bf16x8*>(yp + 32);
      f32x4 acc = {0.f, 0.f, 0.f, 0.f};
      acc = __builtin_amdgcn_mfma_f32_16x16x32_bf16(aW[0], bx0, acc, 0, 0, 0);
      acc = __builtin_amdgcn_mfma_f32_16x16x32_bf16(aW[1], bx1, acc, 0, 0, 0);
      acc = __builtin_amdgcn_mfma_f32_16x16x32_bf16(aW[2], by0, acc, 0, 0, 0);
      acc = __builtin_amdgcn_mfma_f32_16x16x32_bf16(aW[3], by1, acc, 0, 0, 0);
      const int v = vb + l16;  // C/D: col = v-offset, row = c-offset
      if (v < 325) {
#pragma unroll
        for (int r = 0; r < 4; ++r) {
          const int c = cb + quad * 4 + r;
          float res = bf2f(Xr[c * XROW + v]);  // bf16-rounded residual (err ~4e-3)
          out[xbase + c * 20800 + v] = acc[r] + bias_f[r] + res;
        }
      }
    }
  }
}

extern "C" void kernel_launch(void* const* d_in, const int* in_sizes, int n_in,
                              void* d_out, int out_size, void* d_ws, size_t ws_size,
                              hipStream_t stream) {
  const float* x      = (const float*)d_in[0];
  const float* gso    = (const float*)d_in[1];
  const float* weight = (const float*)d_in[2];
  const float* bias   = (const float*)d_in[3];
  unsigned short* gso_pad = (unsigned short*)d_ws;   // 336*352 bf16
  unsigned short* wt      = gso_pad + VPAD * GROW;   // 2*64*64 bf16

  prep_kernel<<<462, 256, 0, stream>>>(gso, weight, gso_pad, wt);
  gconv_kernel<<<2048, 1024, 0, stream>>>(x, bias, gso_pad, wt, (float*)d_out);
}